// Round 1
// baseline (3913.859 us; speedup 1.0000x reference)
//
#include <hip/hip_runtime.h>

// STGAT fully-fused kernel: one block per 64-ped graph, everything LDS-resident.
// Layouts: all LDS 2-D buffers are [row][lane] with lane = ped (conflict-free,
// lane-contiguous). Weight indices are wave-uniform (lane-independent) so the
// compiler emits s_load -> SGPR-operand v_fma.

#define OBS 8
#define FUT 12
#define NPED 64
#define HT_ 32
#define HG_ 32
#define NZ_ 8
#define HP_ 72
#define NGR 1024
#define NTOT (NGR * NPED)

__device__ __forceinline__ float sigf(float x) { return 1.0f / (1.0f + __expf(-x)); }
__device__ __forceinline__ float tanh_(float x) {
    float e = __expf(2.0f * x);
    return 1.0f - 2.0f / (e + 1.0f);
}

__global__ __launch_bounds__(512, 1)
void stgat_fused(const float* __restrict__ obs,       // (8,N,3)
                 const float* __restrict__ zin,       // (G,8)
                 const float* __restrict__ traj_h0,   // (N,32)
                 const float* __restrict__ traj_c0,
                 const float* __restrict__ graph_h0,
                 const float* __restrict__ graph_c0,
                 const float* __restrict__ w_ih_t,    // (128,3)
                 const float* __restrict__ w_hh_t,    // (128,32)
                 const float* __restrict__ b_ih_t,
                 const float* __restrict__ b_hh_t,
                 const float* __restrict__ g1w,       // (4,32,16)
                 const float* __restrict__ g1as,      // (4,16)
                 const float* __restrict__ g1ad,
                 const float* __restrict__ g1b,       // (16)
                 const float* __restrict__ g2w,       // (64,32)
                 const float* __restrict__ g2as,      // (32)
                 const float* __restrict__ g2ad,
                 const float* __restrict__ g2b,       // (32)
                 const float* __restrict__ w_ih_g,    // (128,32)
                 const float* __restrict__ w_hh_g,    // (128,32)
                 const float* __restrict__ b_ih_g,
                 const float* __restrict__ b_hh_g,
                 const float* __restrict__ w_ih_p,    // (288,2)
                 const float* __restrict__ w_hh_p,    // (288,72)
                 const float* __restrict__ b_ih_p,
                 const float* __restrict__ b_hh_p,
                 const float* __restrict__ w_out,     // (2,72)
                 const float* __restrict__ b_out,     // (2)
                 float* __restrict__ out)             // (12,N,2)
{
    const int g    = blockIdx.x;
    const int lane = threadIdx.x & 63;                     // ped within graph
    const int wv   = __builtin_amdgcn_readfirstlane((int)(threadIdx.x >> 6)); // wave 0..7, SGPR
    const int n    = g * NPED + lane;                      // global ped

    __shared__ float s_th[HT_ * 64];    // traj h, [j][ped]
    __shared__ float s_gh[HG_ * 64];    // graph h
    __shared__ float s_scr[27648];      // 108 KB scratch, phase-overlaid

    // ---- t-loop scratch overlay ----
    float* GATES = s_scr;           // [128][64]
    float* xn    = s_scr + 8192;    // [32][64]
    float* hp1   = s_scr + 10240;   // [64][64]  (h*16+o rows)
    float* s1    = s_scr + 14336;   // [4][64]
    float* d1    = s_scr + 14592;   // [4][64]
    float* x2    = s_scr + 14848;   // [64][64]
    float* hp2   = s_scr + 18944;   // [32][64]
    float* s2    = s_scr + 20992;   // [64]
    float* d2    = s_scr + 21056;   // [64]
    float* gin   = s_scr + 21120;   // [32][64]

    float cT[4], cG[4];             // thread (wv,lane) owns c[j], j = wv*4+r
    #pragma unroll
    for (int r = 0; r < 4; ++r) {
        int j = wv * 4 + r;
        s_th[j * 64 + lane] = traj_h0[n * HT_ + j];
        s_gh[j * 64 + lane] = graph_h0[n * HG_ + j];
        cT[r] = traj_c0[n * HT_ + j];
        cG[r] = graph_c0[n * HG_ + j];
    }
    __syncthreads();

    for (int t = 0; t < OBS; ++t) {
        // ================= traj LSTM gates (wave wv: gates wv*16..+16) =====
        {
            const float x0  = obs[(t * NTOT + n) * 3 + 0];
            const float x1  = obs[(t * NTOT + n) * 3 + 1];
            const float x2v = obs[(t * NTOT + n) * 3 + 2];
            float acc[16];
            #pragma unroll
            for (int q = 0; q < 16; ++q) {
                int gate = wv * 16 + q;
                acc[q] = b_ih_t[gate] + b_hh_t[gate]
                       + w_ih_t[gate * 3 + 0] * x0
                       + w_ih_t[gate * 3 + 1] * x1
                       + w_ih_t[gate * 3 + 2] * x2v;
            }
            for (int k8 = 0; k8 < 4; ++k8) {
                float hk[8];
                #pragma unroll
                for (int i = 0; i < 8; ++i) hk[i] = s_th[(k8 * 8 + i) * 64 + lane];
                #pragma unroll
                for (int q = 0; q < 16; ++q) {
                    #pragma unroll
                    for (int i = 0; i < 8; ++i)
                        acc[q] += w_hh_t[(wv * 16 + q) * HT_ + k8 * 8 + i] * hk[i];
                }
            }
            #pragma unroll
            for (int q = 0; q < 16; ++q) GATES[(wv * 16 + q) * 64 + lane] = acc[q];
        }
        __syncthreads();
        // ================= traj update (thread owns j = wv*4+r) ============
        #pragma unroll
        for (int r = 0; r < 4; ++r) {
            int j = wv * 4 + r;
            float gi = GATES[(j)      * 64 + lane];
            float gf = GATES[(32 + j) * 64 + lane];
            float gg = GATES[(64 + j) * 64 + lane];
            float go = GATES[(96 + j) * 64 + lane];
            float c = sigf(gf) * cT[r] + sigf(gi) * tanh_(gg);
            cT[r] = c;
            s_th[j * 64 + lane] = sigf(go) * tanh_(c);
        }
        __syncthreads();
        // ================= inorm(traj_h) -> xn (over 64 peds per feature) ==
        #pragma unroll
        for (int r = 0; r < 4; ++r) {
            int f = wv * 4 + r;
            float v = s_th[f * 64 + lane];
            float sm = v, sq = v * v;
            for (int m = 1; m < 64; m <<= 1) { sm += __shfl_xor(sm, m); sq += __shfl_xor(sq, m); }
            float mean = sm * (1.0f / 64.0f);
            float var  = sq * (1.0f / 64.0f) - mean * mean;
            xn[f * 64 + lane] = (v - mean) * rsqrtf(var + 1e-5f);
        }
        __syncthreads();
        // ================= GAT1 projection: hp1[h*16+o][n] =================
        {
            const int h_ = wv >> 1;
            const int o0 = (wv & 1) * 8;
            float acc[8];
            #pragma unroll
            for (int q = 0; q < 8; ++q) acc[q] = 0.0f;
            for (int k8 = 0; k8 < 4; ++k8) {
                float xk[8];
                #pragma unroll
                for (int i = 0; i < 8; ++i) xk[i] = xn[(k8 * 8 + i) * 64 + lane];
                #pragma unroll
                for (int i = 0; i < 8; ++i) {
                    #pragma unroll
                    for (int q = 0; q < 8; ++q)
                        acc[q] += g1w[h_ * 512 + (k8 * 8 + i) * 16 + o0 + q] * xk[i];
                }
            }
            #pragma unroll
            for (int q = 0; q < 8; ++q) hp1[(h_ * 16 + o0 + q) * 64 + lane] = acc[q];
        }
        __syncthreads();
        // ================= s1, d1 (waves 0-3: s, 4-7: d) ===================
        {
            const int h_ = wv & 3;
            const float* av = (wv < 4) ? g1as : g1ad;
            float acc = 0.0f;
            #pragma unroll
            for (int o = 0; o < 16; ++o) acc += hp1[(h_ * 16 + o) * 64 + lane] * av[h_ * 16 + o];
            float* dst = (wv < 4) ? s1 : d1;
            dst[h_ * 64 + lane] = acc;
        }
        __syncthreads();
        // ============ attn1 softmax + apply + bias + elu -> x2 =============
        {
            const int h_ = wv >> 1;
            const int o0 = (wv & 1) * 8;
            const float sv = s1[h_ * 64 + lane];
            float p[64];
            float mx = -1e30f;
            #pragma unroll
            for (int m = 0; m < 64; ++m) {
                float a = sv + d1[h_ * 64 + m];
                a = (a > 0.0f) ? a : 0.2f * a;
                p[m] = a;
                mx = fmaxf(mx, a);
            }
            float sum = 0.0f;
            #pragma unroll
            for (int m = 0; m < 64; ++m) { float e = __expf(p[m] - mx); p[m] = e; sum += e; }
            float acc[8];
            #pragma unroll
            for (int q = 0; q < 8; ++q) acc[q] = 0.0f;
            #pragma unroll
            for (int m = 0; m < 64; ++m) {
                float pv = p[m];
                #pragma unroll
                for (int q = 0; q < 8; ++q) acc[q] += pv * hp1[(h_ * 16 + o0 + q) * 64 + m];
            }
            float rs = 1.0f / sum;
            #pragma unroll
            for (int q = 0; q < 8; ++q) {
                float v = acc[q] * rs + g1b[o0 + q];
                x2[(h_ * 16 + o0 + q) * 64 + lane] = (v > 0.0f) ? v : (__expf(v) - 1.0f);
            }
        }
        __syncthreads();
        // ================= inorm(x2) in place ==============================
        #pragma unroll
        for (int r = 0; r < 8; ++r) {
            int f = wv * 8 + r;
            float v = x2[f * 64 + lane];
            float sm = v, sq = v * v;
            for (int m = 1; m < 64; m <<= 1) { sm += __shfl_xor(sm, m); sq += __shfl_xor(sq, m); }
            float mean = sm * (1.0f / 64.0f);
            float var  = sq * (1.0f / 64.0f) - mean * mean;
            x2[f * 64 + lane] = (v - mean) * rsqrtf(var + 1e-5f);
        }
        __syncthreads();
        // ================= GAT2 projection: hp2[o][n] ======================
        {
            float acc[4];
            #pragma unroll
            for (int q = 0; q < 4; ++q) acc[q] = 0.0f;
            for (int k8 = 0; k8 < 8; ++k8) {
                float xk[8];
                #pragma unroll
                for (int i = 0; i < 8; ++i) xk[i] = x2[(k8 * 8 + i) * 64 + lane];
                #pragma unroll
                for (int i = 0; i < 8; ++i) {
                    #pragma unroll
                    for (int q = 0; q < 4; ++q)
                        acc[q] += g2w[(k8 * 8 + i) * 32 + wv * 4 + q] * xk[i];
                }
            }
            #pragma unroll
            for (int q = 0; q < 4; ++q) hp2[(wv * 4 + q) * 64 + lane] = acc[q];
        }
        __syncthreads();
        // ================= s2, d2 ==========================================
        if (wv == 0) {
            float acc = 0.0f;
            #pragma unroll
            for (int o = 0; o < 32; ++o) acc += hp2[o * 64 + lane] * g2as[o];
            s2[lane] = acc;
        } else if (wv == 1) {
            float acc = 0.0f;
            #pragma unroll
            for (int o = 0; o < 32; ++o) acc += hp2[o * 64 + lane] * g2ad[o];
            d2[lane] = acc;
        }
        __syncthreads();
        // ============ attn2 softmax + apply + bias -> gin ==================
        {
            const float sv = s2[lane];
            float p[64];
            float mx = -1e30f;
            #pragma unroll
            for (int m = 0; m < 64; ++m) {
                float a = sv + d2[m];
                a = (a > 0.0f) ? a : 0.2f * a;
                p[m] = a;
                mx = fmaxf(mx, a);
            }
            float sum = 0.0f;
            #pragma unroll
            for (int m = 0; m < 64; ++m) { float e = __expf(p[m] - mx); p[m] = e; sum += e; }
            float acc[4];
            #pragma unroll
            for (int q = 0; q < 4; ++q) acc[q] = 0.0f;
            #pragma unroll
            for (int m = 0; m < 64; ++m) {
                float pv = p[m];
                #pragma unroll
                for (int q = 0; q < 4; ++q) acc[q] += pv * hp2[(wv * 4 + q) * 64 + m];
            }
            float rs = 1.0f / sum;
            #pragma unroll
            for (int q = 0; q < 4; ++q)
                gin[(wv * 4 + q) * 64 + lane] = acc[q] * rs + g2b[wv * 4 + q];
        }
        __syncthreads();
        // ================= graph LSTM gates ================================
        {
            float acc[16];
            #pragma unroll
            for (int q = 0; q < 16; ++q) {
                int gate = wv * 16 + q;
                acc[q] = b_ih_g[gate] + b_hh_g[gate];
            }
            for (int k8 = 0; k8 < 4; ++k8) {
                float xk[8], hk[8];
                #pragma unroll
                for (int i = 0; i < 8; ++i) {
                    xk[i] = gin[(k8 * 8 + i) * 64 + lane];
                    hk[i] = s_gh[(k8 * 8 + i) * 64 + lane];
                }
                #pragma unroll
                for (int q = 0; q < 16; ++q) {
                    #pragma unroll
                    for (int i = 0; i < 8; ++i)
                        acc[q] += w_ih_g[(wv * 16 + q) * 32 + k8 * 8 + i] * xk[i]
                                + w_hh_g[(wv * 16 + q) * 32 + k8 * 8 + i] * hk[i];
                }
            }
            #pragma unroll
            for (int q = 0; q < 16; ++q) GATES[(wv * 16 + q) * 64 + lane] = acc[q];
        }
        __syncthreads();
        // ================= graph update ====================================
        #pragma unroll
        for (int r = 0; r < 4; ++r) {
            int j = wv * 4 + r;
            float gi = GATES[(j)      * 64 + lane];
            float gf = GATES[(32 + j) * 64 + lane];
            float gg = GATES[(64 + j) * 64 + lane];
            float go = GATES[(96 + j) * 64 + lane];
            float c = sigf(gf) * cG[r] + sigf(gi) * tanh_(gg);
            cG[r] = c;
            s_gh[j * 64 + lane] = sigf(go) * tanh_(c);
        }
        __syncthreads();
    } // t loop

    // ======================= decoder (12 steps) ============================
    float* hA = s_scr;            // [72][64]
    float* hB = s_scr + 4608;     // [72][64]
    float* PG = s_scr + 9216;     // [288][64]

    float cA[9], cB[9];
    #pragma unroll
    for (int r = 0; r < 9; ++r) { cA[r] = 0.0f; cB[r] = 0.0f; }
    #pragma unroll
    for (int r = 0; r < 9; ++r) {
        int j = wv * 9 + r;
        float va, vb;
        if (j < 32)      { va = s_th[j * 64 + lane];            vb = 0.0f; }
        else if (j < 64) { float gv = s_gh[(j - 32) * 64 + lane]; va = gv; vb = gv; }
        else             { float zv = zin[g * NZ_ + (j - 64)];    va = zv; vb = zv; }
        hA[j * 64 + lane] = va;
        hB[j * 64 + lane] = vb;
    }
    float px0 = obs[(7 * NTOT + n) * 3 + 0];
    float px1 = obs[(7 * NTOT + n) * 3 + 1];
    __syncthreads();

    for (int st = 0; st < FUT; ++st) {
        // ---- gates, state A (wave wv: gates wv*36..+36) ----
        {
            float acc[36];
            #pragma unroll
            for (int q = 0; q < 36; ++q) {
                int gate = wv * 36 + q;
                acc[q] = b_ih_p[gate] + b_hh_p[gate]
                       + w_ih_p[gate * 2 + 0] * px0
                       + w_ih_p[gate * 2 + 1] * px1;
            }
            for (int k8 = 0; k8 < 9; ++k8) {
                float hk[8];
                #pragma unroll
                for (int i = 0; i < 8; ++i) hk[i] = hA[(k8 * 8 + i) * 64 + lane];
                #pragma unroll
                for (int q = 0; q < 36; ++q) {
                    #pragma unroll
                    for (int i = 0; i < 8; ++i)
                        acc[q] += w_hh_p[(wv * 36 + q) * HP_ + k8 * 8 + i] * hk[i];
                }
            }
            #pragma unroll
            for (int q = 0; q < 36; ++q) PG[(wv * 36 + q) * 64 + lane] = acc[q];
        }
        __syncthreads();
        // ---- update A (thread owns j = wv*9+r) ----
        #pragma unroll
        for (int r = 0; r < 9; ++r) {
            int j = wv * 9 + r;
            float gi = PG[(j)       * 64 + lane];
            float gf = PG[(72 + j)  * 64 + lane];
            float gg = PG[(144 + j) * 64 + lane];
            float go = PG[(216 + j) * 64 + lane];
            float c = sigf(gf) * cA[r] + sigf(gi) * tanh_(gg);
            cA[r] = c;
            hA[j * 64 + lane] = sigf(go) * tanh_(c);
        }
        __syncthreads();
        // ---- gates, state B ----
        {
            float acc[36];
            #pragma unroll
            for (int q = 0; q < 36; ++q) {
                int gate = wv * 36 + q;
                acc[q] = b_ih_p[gate] + b_hh_p[gate]
                       + w_ih_p[gate * 2 + 0] * px0
                       + w_ih_p[gate * 2 + 1] * px1;
            }
            for (int k8 = 0; k8 < 9; ++k8) {
                float hk[8];
                #pragma unroll
                for (int i = 0; i < 8; ++i) hk[i] = hB[(k8 * 8 + i) * 64 + lane];
                #pragma unroll
                for (int q = 0; q < 36; ++q) {
                    #pragma unroll
                    for (int i = 0; i < 8; ++i)
                        acc[q] += w_hh_p[(wv * 36 + q) * HP_ + k8 * 8 + i] * hk[i];
                }
            }
            #pragma unroll
            for (int q = 0; q < 36; ++q) PG[(wv * 36 + q) * 64 + lane] = acc[q];
        }
        __syncthreads();
        // ---- update B ----
        #pragma unroll
        for (int r = 0; r < 9; ++r) {
            int j = wv * 9 + r;
            float gi = PG[(j)       * 64 + lane];
            float gf = PG[(72 + j)  * 64 + lane];
            float gg = PG[(144 + j) * 64 + lane];
            float go = PG[(216 + j) * 64 + lane];
            float c = sigf(gf) * cB[r] + sigf(gi) * tanh_(gg);
            cB[r] = c;
            hB[j * 64 + lane] = sigf(go) * tanh_(c);
        }
        __syncthreads();
        // ---- output o = (hA-hB) @ w_out.T + b_out (all waves redundantly) ----
        {
            float o0 = b_out[0], o1 = b_out[1];
            #pragma unroll 8
            for (int j = 0; j < HP_; ++j) {
                float dh = hA[j * 64 + lane] - hB[j * 64 + lane];
                o0 += w_out[j] * dh;
                o1 += w_out[HP_ + j] * dh;
            }
            if (wv == 0) {
                out[(st * NTOT + n) * 2 + 0] = o0;
                out[(st * NTOT + n) * 2 + 1] = o1;
            }
            px0 = o0; px1 = o1;
        }
        __syncthreads();
    }
}

extern "C" void kernel_launch(void* const* d_in, const int* in_sizes, int n_in,
                              void* d_out, int out_size, void* d_ws, size_t ws_size,
                              hipStream_t stream) {
    (void)in_sizes; (void)n_in; (void)out_size; (void)d_ws; (void)ws_size;
    stgat_fused<<<dim3(NGR), dim3(512), 0, stream>>>(
        (const float*)d_in[0],  (const float*)d_in[1],  (const float*)d_in[2],
        (const float*)d_in[3],  (const float*)d_in[4],  (const float*)d_in[5],
        (const float*)d_in[6],  (const float*)d_in[7],  (const float*)d_in[8],
        (const float*)d_in[9],  (const float*)d_in[10], (const float*)d_in[11],
        (const float*)d_in[12], (const float*)d_in[13], (const float*)d_in[14],
        (const float*)d_in[15], (const float*)d_in[16], (const float*)d_in[17],
        (const float*)d_in[18], (const float*)d_in[19], (const float*)d_in[20],
        (const float*)d_in[21], (const float*)d_in[22], (const float*)d_in[23],
        (const float*)d_in[24], (const float*)d_in[25], (const float*)d_in[26],
        (const float*)d_in[27],
        (float*)d_out);
}

// Round 2
// 2785.100 us; speedup vs baseline: 1.4053x; 1.4053x over previous
//
#include <hip/hip_runtime.h>

// STGAT fully-fused: one block per 64-ped graph, all state LDS/register-resident.
// Round 2: (1) attention rewritten two-pass (no p[64] scratch spills),
// (2) LSTM gates kept in registers (wave owns its j's i/f/g/o rows),
// (3) LDS overlay down to ~75KB -> 2 blocks/CU, __launch_bounds__(512,4).

#define OBS 8
#define FUT 12
#define NPED 64
#define HT_ 32
#define HG_ 32
#define NZ_ 8
#define HP_ 72
#define NGR 1024
#define NTOT (NGR * NPED)

__device__ __forceinline__ float sigf(float x) { return 1.0f / (1.0f + __expf(-x)); }
__device__ __forceinline__ float tanh_(float x) {
    float e = __expf(2.0f * x);
    return 1.0f - 2.0f / (e + 1.0f);
}
__device__ __forceinline__ float leaky(float x) { return (x > 0.0f) ? x : 0.2f * x; }

__global__ __launch_bounds__(512, 4)
void stgat_fused(const float* __restrict__ obs,       // (8,N,3)
                 const float* __restrict__ zin,       // (G,8)
                 const float* __restrict__ traj_h0,   // (N,32)
                 const float* __restrict__ traj_c0,
                 const float* __restrict__ graph_h0,
                 const float* __restrict__ graph_c0,
                 const float* __restrict__ w_ih_t,    // (128,3)
                 const float* __restrict__ w_hh_t,    // (128,32)
                 const float* __restrict__ b_ih_t,
                 const float* __restrict__ b_hh_t,
                 const float* __restrict__ g1w,       // (4,32,16)
                 const float* __restrict__ g1as,      // (4,16)
                 const float* __restrict__ g1ad,
                 const float* __restrict__ g1b,       // (16)
                 const float* __restrict__ g2w,       // (64,32)
                 const float* __restrict__ g2as,      // (32)
                 const float* __restrict__ g2ad,
                 const float* __restrict__ g2b,       // (32)
                 const float* __restrict__ w_ih_g,    // (128,32)
                 const float* __restrict__ w_hh_g,    // (128,32)
                 const float* __restrict__ b_ih_g,
                 const float* __restrict__ b_hh_g,
                 const float* __restrict__ w_ih_p,    // (288,2)
                 const float* __restrict__ w_hh_p,    // (288,72)
                 const float* __restrict__ b_ih_p,
                 const float* __restrict__ b_hh_p,
                 const float* __restrict__ w_out,     // (2,72)
                 const float* __restrict__ b_out,     // (2)
                 float* __restrict__ out)             // (12,N,2)
{
    const int g    = blockIdx.x;
    const int lane = threadIdx.x & 63;
    const int wv   = __builtin_amdgcn_readfirstlane((int)(threadIdx.x >> 6));
    const int n    = g * NPED + lane;

    __shared__ float s_th[HT_ * 64];      // 8 KB
    __shared__ float s_gh[HG_ * 64];      // 8 KB
    __shared__ float s_scr[14976];        // ~58.5 KB, phase-overlaid

    // ---- encoder overlay ----
    float* hp1 = s_scr;            // [64][64]
    float* x2  = s_scr + 4096;     // [64][64]
    float* xn  = s_scr + 8192;     // [32][64]
    float* hp2 = s_scr + 10240;    // [32][64]
    float* gin = s_scr + 12288;    // [32][64]
    float* s1  = s_scr + 14336;    // [4][64]
    float* d1  = s_scr + 14592;    // [4][64]
    float* s2  = s_scr + 14848;    // [64]
    float* d2  = s_scr + 14912;    // [64]
    // ---- decoder overlay ----
    float* hA   = s_scr;           // [72][64]  (0..4608)
    float* hB   = s_scr + 4608;    // [72][64]  (4608..9216)
    float* red0 = s_scr + 10240;   // [8][64]
    float* red1 = s_scr + 10752;   // [8][64]
    float* px   = s_scr + 12288;   // [2][64]

    float cT[4], cG[4];
    #pragma unroll
    for (int r = 0; r < 4; ++r) {
        int j = wv * 4 + r;
        s_th[j * 64 + lane] = traj_h0[n * HT_ + j];
        s_gh[j * 64 + lane] = graph_h0[n * HG_ + j];
        cT[r] = traj_c0[n * HT_ + j];
        cG[r] = graph_c0[n * HG_ + j];
    }
    __syncthreads();

    for (int t = 0; t < OBS; ++t) {
        // ===== traj LSTM: wave wv computes i/f/g/o gates for j = wv*4+r ====
        float nh[4];
        {
            const float x0 = obs[(t * NTOT + n) * 3 + 0];
            const float x1 = obs[(t * NTOT + n) * 3 + 1];
            const float xv = obs[(t * NTOT + n) * 3 + 2];
            float acc[16];
            #pragma unroll
            for (int ty = 0; ty < 4; ++ty)
                #pragma unroll
                for (int r = 0; r < 4; ++r) {
                    int gate = ty * 32 + wv * 4 + r;
                    acc[ty * 4 + r] = b_ih_t[gate] + b_hh_t[gate]
                                    + w_ih_t[gate * 3 + 0] * x0
                                    + w_ih_t[gate * 3 + 1] * x1
                                    + w_ih_t[gate * 3 + 2] * xv;
                }
            for (int k8 = 0; k8 < 4; ++k8) {
                float hk[8];
                #pragma unroll
                for (int i = 0; i < 8; ++i) hk[i] = s_th[(k8 * 8 + i) * 64 + lane];
                #pragma unroll
                for (int ty = 0; ty < 4; ++ty)
                    #pragma unroll
                    for (int r = 0; r < 4; ++r)
                        #pragma unroll
                        for (int i = 0; i < 8; ++i)
                            acc[ty * 4 + r] += w_hh_t[(ty * 32 + wv * 4 + r) * HT_ + k8 * 8 + i] * hk[i];
            }
            #pragma unroll
            for (int r = 0; r < 4; ++r) {
                float c = sigf(acc[4 + r]) * cT[r] + sigf(acc[r]) * tanh_(acc[8 + r]);
                cT[r] = c;
                nh[r] = sigf(acc[12 + r]) * tanh_(c);
            }
        }
        __syncthreads();                       // all reads of old s_th done
        // write h + fused inorm (value is in-register; norm = 64-lane shuffle)
        #pragma unroll
        for (int r = 0; r < 4; ++r) {
            int f = wv * 4 + r;
            s_th[f * 64 + lane] = nh[r];
            float v = nh[r];
            float sm = v, sq = v * v;
            #pragma unroll
            for (int m = 1; m < 64; m <<= 1) { sm += __shfl_xor(sm, m); sq += __shfl_xor(sq, m); }
            float mean = sm * (1.0f / 64.0f);
            float var  = sq * (1.0f / 64.0f) - mean * mean;
            xn[f * 64 + lane] = (v - mean) * rsqrtf(var + 1e-5f);
        }
        __syncthreads();
        // ===== GAT1 projection: wave (h_, o0) -> hp1 rows h_*16+o0..+8 =====
        {
            const int h_ = wv >> 1;
            const int o0 = (wv & 1) * 8;
            float acc[8];
            #pragma unroll
            for (int q = 0; q < 8; ++q) acc[q] = 0.0f;
            for (int k8 = 0; k8 < 4; ++k8) {
                float xk[8];
                #pragma unroll
                for (int i = 0; i < 8; ++i) xk[i] = xn[(k8 * 8 + i) * 64 + lane];
                #pragma unroll
                for (int i = 0; i < 8; ++i)
                    #pragma unroll
                    for (int q = 0; q < 8; ++q)
                        acc[q] += g1w[h_ * 512 + (k8 * 8 + i) * 16 + o0 + q] * xk[i];
            }
            #pragma unroll
            for (int q = 0; q < 8; ++q) hp1[(h_ * 16 + o0 + q) * 64 + lane] = acc[q];
        }
        __syncthreads();
        // ===== s1, d1 =====
        {
            const int h_ = wv & 3;
            const float* av = (wv < 4) ? g1as : g1ad;
            float acc = 0.0f;
            #pragma unroll
            for (int o = 0; o < 16; ++o) acc += hp1[(h_ * 16 + o) * 64 + lane] * av[h_ * 16 + o];
            float* dst = (wv < 4) ? s1 : d1;
            dst[h_ * 64 + lane] = acc;
        }
        __syncthreads();
        // ===== attn1: two-pass softmax-apply (no p[] array) + elu + inorm ===
        {
            const int h_ = wv >> 1;
            const int o0 = (wv & 1) * 8;
            const float sv = s1[h_ * 64 + lane];
            float mx = -1e30f;
            #pragma unroll
            for (int m4 = 0; m4 < 16; ++m4) {
                float4 dv = *reinterpret_cast<const float4*>(&d1[h_ * 64 + m4 * 4]);
                mx = fmaxf(mx, leaky(sv + dv.x));
                mx = fmaxf(mx, leaky(sv + dv.y));
                mx = fmaxf(mx, leaky(sv + dv.z));
                mx = fmaxf(mx, leaky(sv + dv.w));
            }
            float sum = 0.0f;
            float acc[8];
            #pragma unroll
            for (int q = 0; q < 8; ++q) acc[q] = 0.0f;
            #pragma unroll
            for (int m4 = 0; m4 < 16; ++m4) {
                float4 dv = *reinterpret_cast<const float4*>(&d1[h_ * 64 + m4 * 4]);
                float e0 = __expf(leaky(sv + dv.x) - mx);
                float e1 = __expf(leaky(sv + dv.y) - mx);
                float e2 = __expf(leaky(sv + dv.z) - mx);
                float e3 = __expf(leaky(sv + dv.w) - mx);
                sum += e0 + e1 + e2 + e3;
                #pragma unroll
                for (int q = 0; q < 8; ++q) {
                    float4 hv = *reinterpret_cast<const float4*>(&hp1[(h_ * 16 + o0 + q) * 64 + m4 * 4]);
                    acc[q] += e0 * hv.x + e1 * hv.y + e2 * hv.z + e3 * hv.w;
                }
            }
            float rs = 1.0f / sum;
            #pragma unroll
            for (int q = 0; q < 8; ++q) {
                float v = acc[q] * rs + g1b[o0 + q];
                v = (v > 0.0f) ? v : (__expf(v) - 1.0f);          // elu
                float sm = v, sq = v * v;                          // fused inorm
                #pragma unroll
                for (int m = 1; m < 64; m <<= 1) { sm += __shfl_xor(sm, m); sq += __shfl_xor(sq, m); }
                float mean = sm * (1.0f / 64.0f);
                float var  = sq * (1.0f / 64.0f) - mean * mean;
                x2[(h_ * 16 + o0 + q) * 64 + lane] = (v - mean) * rsqrtf(var + 1e-5f);
            }
        }
        __syncthreads();
        // ===== GAT2 projection: wave wv -> hp2 rows wv*4..+4 =====
        {
            float acc[4];
            #pragma unroll
            for (int q = 0; q < 4; ++q) acc[q] = 0.0f;
            for (int k8 = 0; k8 < 8; ++k8) {
                float xk[8];
                #pragma unroll
                for (int i = 0; i < 8; ++i) xk[i] = x2[(k8 * 8 + i) * 64 + lane];
                #pragma unroll
                for (int i = 0; i < 8; ++i)
                    #pragma unroll
                    for (int q = 0; q < 4; ++q)
                        acc[q] += g2w[(k8 * 8 + i) * 32 + wv * 4 + q] * xk[i];
            }
            #pragma unroll
            for (int q = 0; q < 4; ++q) hp2[(wv * 4 + q) * 64 + lane] = acc[q];
        }
        __syncthreads();
        // ===== s2, d2 =====
        if (wv == 0) {
            float acc = 0.0f;
            #pragma unroll
            for (int o = 0; o < 32; ++o) acc += hp2[o * 64 + lane] * g2as[o];
            s2[lane] = acc;
        } else if (wv == 1) {
            float acc = 0.0f;
            #pragma unroll
            for (int o = 0; o < 32; ++o) acc += hp2[o * 64 + lane] * g2ad[o];
            d2[lane] = acc;
        }
        __syncthreads();
        // ===== attn2: two-pass, wave wv -> gin rows wv*4..+4 =====
        {
            const float sv = s2[lane];
            float mx = -1e30f;
            #pragma unroll
            for (int m4 = 0; m4 < 16; ++m4) {
                float4 dv = *reinterpret_cast<const float4*>(&d2[m4 * 4]);
                mx = fmaxf(mx, leaky(sv + dv.x));
                mx = fmaxf(mx, leaky(sv + dv.y));
                mx = fmaxf(mx, leaky(sv + dv.z));
                mx = fmaxf(mx, leaky(sv + dv.w));
            }
            float sum = 0.0f;
            float acc[4];
            #pragma unroll
            for (int q = 0; q < 4; ++q) acc[q] = 0.0f;
            #pragma unroll
            for (int m4 = 0; m4 < 16; ++m4) {
                float4 dv = *reinterpret_cast<const float4*>(&d2[m4 * 4]);
                float e0 = __expf(leaky(sv + dv.x) - mx);
                float e1 = __expf(leaky(sv + dv.y) - mx);
                float e2 = __expf(leaky(sv + dv.z) - mx);
                float e3 = __expf(leaky(sv + dv.w) - mx);
                sum += e0 + e1 + e2 + e3;
                #pragma unroll
                for (int q = 0; q < 4; ++q) {
                    float4 hv = *reinterpret_cast<const float4*>(&hp2[(wv * 4 + q) * 64 + m4 * 4]);
                    acc[q] += e0 * hv.x + e1 * hv.y + e2 * hv.z + e3 * hv.w;
                }
            }
            float rs = 1.0f / sum;
            #pragma unroll
            for (int q = 0; q < 4; ++q)
                gin[(wv * 4 + q) * 64 + lane] = acc[q] * rs + g2b[wv * 4 + q];
        }
        __syncthreads();
        // ===== graph LSTM: gates in regs =====
        float ng[4];
        {
            float acc[16];
            #pragma unroll
            for (int ty = 0; ty < 4; ++ty)
                #pragma unroll
                for (int r = 0; r < 4; ++r) {
                    int gate = ty * 32 + wv * 4 + r;
                    acc[ty * 4 + r] = b_ih_g[gate] + b_hh_g[gate];
                }
            for (int k8 = 0; k8 < 4; ++k8) {
                float xk[8], hk[8];
                #pragma unroll
                for (int i = 0; i < 8; ++i) {
                    xk[i] = gin[(k8 * 8 + i) * 64 + lane];
                    hk[i] = s_gh[(k8 * 8 + i) * 64 + lane];
                }
                #pragma unroll
                for (int ty = 0; ty < 4; ++ty)
                    #pragma unroll
                    for (int r = 0; r < 4; ++r)
                        #pragma unroll
                        for (int i = 0; i < 8; ++i)
                            acc[ty * 4 + r] += w_ih_g[(ty * 32 + wv * 4 + r) * 32 + k8 * 8 + i] * xk[i]
                                             + w_hh_g[(ty * 32 + wv * 4 + r) * 32 + k8 * 8 + i] * hk[i];
            }
            #pragma unroll
            for (int r = 0; r < 4; ++r) {
                float c = sigf(acc[4 + r]) * cG[r] + sigf(acc[r]) * tanh_(acc[8 + r]);
                cG[r] = c;
                ng[r] = sigf(acc[12 + r]) * tanh_(c);
            }
        }
        __syncthreads();                       // all reads of old s_gh done
        #pragma unroll
        for (int r = 0; r < 4; ++r) s_gh[(wv * 4 + r) * 64 + lane] = ng[r];
        // no trailing barrier: next phase that reads/writes s_gh is many barriers away
    } // t loop

    __syncthreads();                           // fence final s_gh writes

    // ======================= decoder (12 steps) ============================
    float cA[9], cB[9];
    #pragma unroll
    for (int r = 0; r < 9; ++r) { cA[r] = 0.0f; cB[r] = 0.0f; }
    #pragma unroll
    for (int r = 0; r < 9; ++r) {
        int j = wv * 9 + r;
        float va, vb;
        if (j < 32)      { va = s_th[j * 64 + lane];              vb = 0.0f; }
        else if (j < 64) { float gv = s_gh[(j - 32) * 64 + lane]; va = gv; vb = gv; }
        else             { float zv = zin[g * NZ_ + (j - 64)];    va = zv; vb = zv; }
        hA[j * 64 + lane] = va;
        hB[j * 64 + lane] = vb;
    }
    if (wv == 0) {
        px[lane]      = obs[(7 * NTOT + n) * 3 + 0];
        px[64 + lane] = obs[(7 * NTOT + n) * 3 + 1];
    }
    __syncthreads();

    for (int st = 0; st < FUT; ++st) {
        const float px0 = px[lane];
        const float px1 = px[64 + lane];
        float nhA[9], nhB[9];
        // ---- gates+update A (registers only; reads hA) ----
        {
            float acc[36];
            #pragma unroll
            for (int ty = 0; ty < 4; ++ty)
                #pragma unroll
                for (int r = 0; r < 9; ++r) {
                    int gate = ty * 72 + wv * 9 + r;
                    acc[ty * 9 + r] = b_ih_p[gate] + b_hh_p[gate]
                                    + w_ih_p[gate * 2 + 0] * px0
                                    + w_ih_p[gate * 2 + 1] * px1;
                }
            for (int k8 = 0; k8 < 9; ++k8) {
                float hk[8];
                #pragma unroll
                for (int i = 0; i < 8; ++i) hk[i] = hA[(k8 * 8 + i) * 64 + lane];
                #pragma unroll
                for (int ty = 0; ty < 4; ++ty)
                    #pragma unroll
                    for (int r = 0; r < 9; ++r)
                        #pragma unroll
                        for (int i = 0; i < 8; ++i)
                            acc[ty * 9 + r] += w_hh_p[(ty * 72 + wv * 9 + r) * HP_ + k8 * 8 + i] * hk[i];
            }
            #pragma unroll
            for (int r = 0; r < 9; ++r) {
                float c = sigf(acc[9 + r]) * cA[r] + sigf(acc[r]) * tanh_(acc[18 + r]);
                cA[r] = c;
                nhA[r] = sigf(acc[27 + r]) * tanh_(c);
            }
        }
        // ---- gates+update B (reads hB) ----
        {
            float acc[36];
            #pragma unroll
            for (int ty = 0; ty < 4; ++ty)
                #pragma unroll
                for (int r = 0; r < 9; ++r) {
                    int gate = ty * 72 + wv * 9 + r;
                    acc[ty * 9 + r] = b_ih_p[gate] + b_hh_p[gate]
                                    + w_ih_p[gate * 2 + 0] * px0
                                    + w_ih_p[gate * 2 + 1] * px1;
                }
            for (int k8 = 0; k8 < 9; ++k8) {
                float hk[8];
                #pragma unroll
                for (int i = 0; i < 8; ++i) hk[i] = hB[(k8 * 8 + i) * 64 + lane];
                #pragma unroll
                for (int ty = 0; ty < 4; ++ty)
                    #pragma unroll
                    for (int r = 0; r < 9; ++r)
                        #pragma unroll
                        for (int i = 0; i < 8; ++i)
                            acc[ty * 9 + r] += w_hh_p[(ty * 72 + wv * 9 + r) * HP_ + k8 * 8 + i] * hk[i];
            }
            #pragma unroll
            for (int r = 0; r < 9; ++r) {
                float c = sigf(acc[9 + r]) * cB[r] + sigf(acc[r]) * tanh_(acc[18 + r]);
                cB[r] = c;
                nhB[r] = sigf(acc[27 + r]) * tanh_(c);
            }
        }
        // ---- local partial of output dot ----
        float po0 = 0.0f, po1 = 0.0f;
        #pragma unroll
        for (int r = 0; r < 9; ++r) {
            float dh = nhA[r] - nhB[r];
            po0 += w_out[wv * 9 + r] * dh;
            po1 += w_out[HP_ + wv * 9 + r] * dh;
        }
        __syncthreads();                       // B1: all reads of hA/hB/px done
        #pragma unroll
        for (int r = 0; r < 9; ++r) {
            hA[(wv * 9 + r) * 64 + lane] = nhA[r];
            hB[(wv * 9 + r) * 64 + lane] = nhB[r];
        }
        red0[wv * 64 + lane] = po0;
        red1[wv * 64 + lane] = po1;
        __syncthreads();                       // B2
        if (wv == 0) {
            float o0 = b_out[0], o1 = b_out[1];
            #pragma unroll
            for (int w = 0; w < 8; ++w) { o0 += red0[w * 64 + lane]; o1 += red1[w * 64 + lane]; }
            out[(st * NTOT + n) * 2 + 0] = o0;
            out[(st * NTOT + n) * 2 + 1] = o1;
            px[lane]      = o0;
            px[64 + lane] = o1;
        }
        __syncthreads();                       // B3: px visible to all
    }
}

extern "C" void kernel_launch(void* const* d_in, const int* in_sizes, int n_in,
                              void* d_out, int out_size, void* d_ws, size_t ws_size,
                              hipStream_t stream) {
    (void)in_sizes; (void)n_in; (void)out_size; (void)d_ws; (void)ws_size;
    stgat_fused<<<dim3(NGR), dim3(512), 0, stream>>>(
        (const float*)d_in[0],  (const float*)d_in[1],  (const float*)d_in[2],
        (const float*)d_in[3],  (const float*)d_in[4],  (const float*)d_in[5],
        (const float*)d_in[6],  (const float*)d_in[7],  (const float*)d_in[8],
        (const float*)d_in[9],  (const float*)d_in[10], (const float*)d_in[11],
        (const float*)d_in[12], (const float*)d_in[13], (const float*)d_in[14],
        (const float*)d_in[15], (const float*)d_in[16], (const float*)d_in[17],
        (const float*)d_in[18], (const float*)d_in[19], (const float*)d_in[20],
        (const float*)d_in[21], (const float*)d_in[22], (const float*)d_in[23],
        (const float*)d_in[24], (const float*)d_in[25], (const float*)d_in[26],
        (const float*)d_in[27],
        (float*)d_out);
}